// Round 6
// baseline (962.350 us; speedup 1.0000x reference)
//
#include <hip/hip_runtime.h>
#include <hip/hip_bf16.h>
#include <stdint.h>

typedef __hip_bfloat16 bf16;
typedef __attribute__((ext_vector_type(8))) short short8;
typedef __attribute__((ext_vector_type(4))) float f32x4;

// Problem constants
#define S_LEN   4096
#define BATCH   8
#define D_MODEL 1280
#define NHEADS  16
#define DHEAD   80
#define WIN     64
#define NWIN    (S_LEN / WIN)            // 64
#define QKV_N   (3 * D_MODEL)            // 3840
#define ATT_K   (WIN * DHEAD)            // 5120
#define M_QKV   (S_LEN * BATCH)          // 32768
#define M_PROJ  (NWIN * NHEADS * BATCH)  // 8192
#define OUT_ELEMS ((size_t)M_PROJ * D_MODEL) // 10,485,760

// canon segment sizes (in 4-element chunks)
#define NX4   (M_QKV * D_MODEL / 4)
#define NQW4  (QKV_N * D_MODEL / 4)
#define NPW4  (D_MODEL * ATT_K / 4)
#define NQB4  (QKV_N / 4)
#define NPB4  (D_MODEL / 4)
#define TOT4  (NX4 + NQW4 + NPW4 + NQB4 + NPB4)

__device__ __forceinline__ float bf2f(unsigned short b) {
    union { unsigned int i; float f; } v;
    v.i = ((unsigned int)b) << 16;
    return v.f;
}

__device__ __forceinline__ unsigned short f2bf(float f) {
    __hip_bfloat16 h = __float2bfloat16(f);
    return *reinterpret_cast<unsigned short*>(&h);
}

// ---------------------------------------------------------------------------
// Dtype detection (fp32 inputs -> flag=1, bf16 -> flag=0).
// ---------------------------------------------------------------------------
__global__ void detect_dtype(const unsigned short* __restrict__ x,
                             int* __restrict__ flag) {
    const int lane = threadIdx.x;  // 64
    int big = 0;
    for (int j = lane; j < 256; j += 64) {
        unsigned short u = x[2 * j];
        int e = (u >> 7) & 0xFF;
        big += (e >= 135) ? 1 : 0;
    }
#pragma unroll
    for (int m = 1; m < 64; m <<= 1) big += __shfl_xor(big, m, 64);
    if (lane == 0) *flag = (big >= 8) ? 1 : 0;
}

// ---------------------------------------------------------------------------
// One merged canonicalization kernel for all 5 float inputs -> bf16 copies.
// ---------------------------------------------------------------------------
__global__ __launch_bounds__(256) void canon_all(
    const void* __restrict__ x,  const void* __restrict__ qw,
    const void* __restrict__ pw, const void* __restrict__ qb,
    const void* __restrict__ pb,
    bf16* __restrict__ xc, bf16* __restrict__ qwc, bf16* __restrict__ pwc,
    bf16* __restrict__ qbc, bf16* __restrict__ pbc,
    const int* __restrict__ flag) {
    const int f = *flag;
    const long i = (long)blockIdx.x * 256 + threadIdx.x;
    if (i >= TOT4) return;
    const void* src; bf16* dst; long j;
    if (i < NX4)                        { src = x;  dst = xc;  j = i; }
    else if (i < NX4 + NQW4)            { src = qw; dst = qwc; j = i - NX4; }
    else if (i < NX4 + NQW4 + NPW4)     { src = pw; dst = pwc; j = i - NX4 - NQW4; }
    else if (i < NX4 + NQW4 + NPW4 + NQB4) { src = qb; dst = qbc; j = i - NX4 - NQW4 - NPW4; }
    else                                { src = pb; dst = pbc; j = i - NX4 - NQW4 - NPW4 - NQB4; }
    if (f) {
        const float4 v = ((const float4*)src)[j];
        ushort4 o;
        o.x = f2bf(v.x); o.y = f2bf(v.y); o.z = f2bf(v.z); o.w = f2bf(v.w);
        ((ushort4*)dst)[j] = o;
    } else {
        ((ushort4*)dst)[j] = ((const ushort4*)src)[j];
    }
}

__device__ __forceinline__ void gload16(const bf16* g, bf16* l) {
    __builtin_amdgcn_global_load_lds(
        (const __attribute__((address_space(1))) void*)g,
        (__attribute__((address_space(3))) void*)l, 16, 0, 0);
}

// ---------------------------------------------------------------------------
// 256x256 8-phase BT GEMM (m201-style schedule, plain HIP).
// C[M,N] = A[M,K] @ B[N,K]^T + bias[N]. bf16 in, fp32 accumulate.
//
// Geometry: BM=BN=256, BK=64, 512 threads = 8 waves in 2(M)x4(N);
// each wave owns 128x64 output via acc[8][4] f32x4 (16x16x32 bf16 MFMA).
// LDS: double-buffered A,B tiles [2][256][64] bf16 = 128 KiB (1 block/CU).
// Swizzle: 16B chunks, physical chunk = logical ^ (row&7). Staged with
// LINEAR LDS dest + inverse-swizzled GLOBAL source (global_load_lds rule),
// read back with the same XOR -> full 32-bank spread (free 2-way only).
//
// Schedule per K-tile kt (buffer cur = kt&1), quadrant = 128x128 of C:
//   P1: ds A(mh0) 8x + B(nh0) 4x | stage B-h1 of kt+1 | bar | lgkm(0) |
//       prio1 16 MFMA Q(0,0) prio0 | bar
//   P2: ds B(nh1) 4x             | stage A-h0 of kt+2 | ... Q(0,1) ...
//   P3: ds A(mh1) 8x             | stage B-h0 of kt+2 | ... Q(1,1) ...
//   P4: (frags cached in regs)   | stage A-h1 of kt+2 | bar |
//       prio1 16 MFMA Q(1,0) prio0 | GATE | bar
// GATE = s_waitcnt vmcnt(6): the 6 newest loads are kt+2's 3 half-tiles,
// so everything through kt+1's last half-tile is resident before any wave
// reads kt+1. Overwrite safety is STRICT (no latency assumption): each LDS
// half's last ds_read is >=1 barrier before the stage that overwrites it
// (A-h0 read P1, overwritten P2; B-h0 read P1, ovw P3; B-h1 read P2, ovw
// next kt's P1 [other buffer]; A-h1 read P3, ovw P4).
// Prologue: stage kt0 (4 halves) + kt1 (3 halves), vmcnt(6), barrier.
// Epilogue gates: kt==nt-2 -> vmcnt(0); kt==nt-1 -> none.
// ---------------------------------------------------------------------------
__global__ __launch_bounds__(512) void gemm_bt_bias_256(
    const bf16* __restrict__ A, const bf16* __restrict__ B,
    const bf16* __restrict__ bias, void* __restrict__ Cout,
    int M, int N, int K, const int* __restrict__ out_f32)
{
    __shared__ bf16 sA[2][256 * 64];
    __shared__ bf16 sB[2][256 * 64];

    const int t    = threadIdx.x;        // 0..511
    const int lane = t & 63;
    const int wave = t >> 6;             // 0..7
    const int wm   = wave >> 2;          // 0..1
    const int wn   = wave & 3;           // 0..3
    const int quad = lane >> 4;
    const int l16  = lane & 15;
    const int l7   = l16 & 7;

    // Block swizzle: XCD slab (bijective; both grids are multiples of 8)
    // + GROUP_M chunks inside the slab for L2 reuse.
    const int B_nb = N >> 8, B_mb = M >> 8;
    const int mpx  = B_mb >> 3;                 // m-blocks per XCD
    const int gm   = (mpx >= 8) ? 8 : mpx;      // 8 for QKV, 4 for proj
    const int gid  = blockIdx.x;
    const int xcd  = gid & 7;
    const int per  = gid >> 3;
    const int grp  = per / (gm * B_nb);
    const int rem  = per - grp * (gm * B_nb);
    const int bn   = rem / gm;
    const int bm   = xcd * mpx + grp * gm + (rem - bn * gm);

    // Staging: thread t covers row t>>3 (of 64/issue), physical chunk t&7,
    // global chunk (t&7)^(row&7). Row offsets below are multiples of 8, so
    // tchunk is issue-invariant.
    const int trow   = t >> 3;
    const int tchunk = (t & 7) ^ (trow & 7);
    const bf16* Ag = A + (size_t)(bm * 256 + trow) * K + tchunk * 8;
    const bf16* Bg = B + (size_t)(bn * 256 + trow) * K + tchunk * 8;
    const int nt = K >> 6;

#define STAGE(hx, kt_)                                                       \
  do {                                                                       \
    const int _b = (kt_) & 1;                                                \
    if ((hx) == 0 || (hx) == 2) {                                            \
      const int _h = ((hx) == 2) ? 128 : 0;                                  \
      gload16(Ag + (size_t)(_h) * K + (size_t)(kt_) * 64,                    \
              &sA[_b][_h * 64 + wave * 512]);                                \
      gload16(Ag + (size_t)(_h + 64) * K + (size_t)(kt_) * 64,               \
              &sA[_b][(_h + 64) * 64 + wave * 512]);                         \
    } else {                                                                 \
      const int _h = ((hx) == 3) ? 128 : 0;                                  \
      gload16(Bg + (size_t)(_h) * K + (size_t)(kt_) * 64,                    \
              &sB[_b][_h * 64 + wave * 512]);                                \
      gload16(Bg + (size_t)(_h + 64) * K + (size_t)(kt_) * 64,               \
              &sB[_b][(_h + 64) * 64 + wave * 512]);                         \
    }                                                                        \
  } while (0)

    f32x4 acc[8][4];
#pragma unroll
    for (int i = 0; i < 8; ++i)
#pragma unroll
        for (int j = 0; j < 4; ++j)
            acc[i][j] = (f32x4){0.f, 0.f, 0.f, 0.f};

    short8 af[4][2];        // A frags of the active mh (i, kchunk)
    short8 bfr[2][2][2];    // B frags of BOTH nh halves ([nh][jj][kchunk])
    const int pc0 = quad ^ l7;          // swizzled chunk, kchunk 0
    const int pc1 = (quad + 4) ^ l7;    // swizzled chunk, kchunk 1

#define LDA(mh)                                                              \
  do {                                                                       \
    const bf16* _ab = &sA[cur][((mh) * 128 + wm * 64 + l16) * 64];           \
    _Pragma("unroll")                                                        \
    for (int _i = 0; _i < 4; ++_i) {                                         \
      af[_i][0] = *(const short8*)(_ab + _i * 1024 + pc0 * 8);               \
      af[_i][1] = *(const short8*)(_ab + _i * 1024 + pc1 * 8);               \
    }                                                                        \
  } while (0)

#define LDB(nh)                                                              \
  do {                                                                       \
    const bf16* _bb = &sB[cur][((nh) * 128 + wn * 32 + l16) * 64];           \
    _Pragma("unroll")                                                        \
    for (int _j = 0; _j < 2; ++_j) {                                         \
      bfr[nh][_j][0] = *(const short8*)(_bb + _j * 1024 + pc0 * 8);          \
      bfr[nh][_j][1] = *(const short8*)(_bb + _j * 1024 + pc1 * 8);          \
    }                                                                        \
  } while (0)

#define MFMA_Q(mh, nh)                                                       \
  do {                                                                       \
    _Pragma("unroll")                                                        \
    for (int _i = 0; _i < 4; ++_i)                                           \
      _Pragma("unroll")                                                      \
      for (int _j = 0; _j < 2; ++_j) {                                       \
        acc[(mh) * 4 + _i][(nh) * 2 + _j] =                                  \
            __builtin_amdgcn_mfma_f32_16x16x32_bf16(                         \
                af[_i][0], bfr[nh][_j][0],                                   \
                acc[(mh) * 4 + _i][(nh) * 2 + _j], 0, 0, 0);                 \
        acc[(mh) * 4 + _i][(nh) * 2 + _j] =                                  \
            __builtin_amdgcn_mfma_f32_16x16x32_bf16(                         \
                af[_i][1], bfr[nh][_j][1],                                   \
                acc[(mh) * 4 + _i][(nh) * 2 + _j], 0, 0, 0);                 \
      }                                                                      \
  } while (0)

    // Prologue: kt0 fully + kt1 halves 0..2 (7 half-tiles = 14 loads),
    // then guarantee kt0 resident (newest 6 = kt1's loads).
    STAGE(0, 0); STAGE(1, 0); STAGE(2, 0); STAGE(3, 0);
    if (nt > 1) {
        STAGE(0, 1); STAGE(1, 1); STAGE(2, 1);
        asm volatile("s_waitcnt vmcnt(6)" ::: "memory");
    } else {
        asm volatile("s_waitcnt vmcnt(0)" ::: "memory");
    }
    __builtin_amdgcn_s_barrier();

    int cur = 0;
    for (int kt = 0; kt < nt; ++kt) {
        // ---- P1: Q(0,0)
        LDA(0); LDB(0);
        if (kt + 1 < nt) STAGE(3, kt + 1);
        __builtin_amdgcn_s_barrier();
        asm volatile("s_waitcnt lgkmcnt(0)" ::: "memory");
        __builtin_amdgcn_s_setprio(1);
        MFMA_Q(0, 0);
        __builtin_amdgcn_s_setprio(0);
        __builtin_amdgcn_s_barrier();
        // ---- P2: Q(0,1)
        LDB(1);
        if (kt + 2 < nt) STAGE(0, kt + 2);
        __builtin_amdgcn_s_barrier();
        asm volatile("s_waitcnt lgkmcnt(0)" ::: "memory");
        __builtin_amdgcn_s_setprio(1);
        MFMA_Q(0, 1);
        __builtin_amdgcn_s_setprio(0);
        __builtin_amdgcn_s_barrier();
        // ---- P3: Q(1,1)
        LDA(1);
        if (kt + 2 < nt) STAGE(1, kt + 2);
        __builtin_amdgcn_s_barrier();
        asm volatile("s_waitcnt lgkmcnt(0)" ::: "memory");
        __builtin_amdgcn_s_setprio(1);
        MFMA_Q(1, 1);
        __builtin_amdgcn_s_setprio(0);
        __builtin_amdgcn_s_barrier();
        // ---- P4: Q(1,0) — all frags already in registers
        if (kt + 2 < nt) STAGE(2, kt + 2);
        __builtin_amdgcn_s_barrier();
        __builtin_amdgcn_s_setprio(1);
        MFMA_Q(1, 0);
        __builtin_amdgcn_s_setprio(0);
        if (kt < nt - 2)       asm volatile("s_waitcnt vmcnt(6)" ::: "memory");
        else if (kt == nt - 2) asm volatile("s_waitcnt vmcnt(0)" ::: "memory");
        __builtin_amdgcn_s_barrier();
        cur ^= 1;
    }
#undef STAGE
#undef LDA
#undef LDB
#undef MFMA_Q

    // Epilogue: C/D layout col = lane&15, row = quad*4 + reg.
    const int outf = out_f32 ? *out_f32 : 0;
    const int crow0 = bm * 256 + wm * 64 + quad * 4;
    const int ccol0 = bn * 256 + wn * 32 + l16;
    if (outf) {
        float* Cf = (float*)Cout;
#pragma unroll
        for (int mh = 0; mh < 2; ++mh)
#pragma unroll
        for (int nh = 0; nh < 2; ++nh)
#pragma unroll
        for (int j = 0; j < 2; ++j) {
            const int col = ccol0 + nh * 128 + j * 16;
            const float bv = bf2f(*(const unsigned short*)&bias[col]);
#pragma unroll
            for (int i = 0; i < 4; ++i) {
                const int row = crow0 + mh * 128 + i * 16;
#pragma unroll
                for (int r = 0; r < 4; ++r)
                    Cf[(size_t)(row + r) * N + col] =
                        acc[mh * 4 + i][nh * 2 + j][r] + bv;
            }
        }
    } else {
        bf16* Cb = (bf16*)Cout;
#pragma unroll
        for (int mh = 0; mh < 2; ++mh)
#pragma unroll
        for (int nh = 0; nh < 2; ++nh)
#pragma unroll
        for (int j = 0; j < 2; ++j) {
            const int col = ccol0 + nh * 128 + j * 16;
            const float bv = bf2f(*(const unsigned short*)&bias[col]);
#pragma unroll
            for (int i = 0; i < 4; ++i) {
                const int row = crow0 + mh * 128 + i * 16;
#pragma unroll
                for (int r = 0; r < 4; ++r)
                    Cb[(size_t)(row + r) * N + col] =
                        __float2bfloat16(acc[mh * 4 + i][nh * 2 + j][r] + bv);
            }
        }
    }
}

// ---------------------------------------------------------------------------
// Windowed attention over the head axis. One wave per (si, b) pair.
// ---------------------------------------------------------------------------
__global__ __launch_bounds__(64) void win_attn(
    const bf16* __restrict__ qkv,   // [32768, 3840]
    bf16* __restrict__ aout)        // [8192, 5120]
{
    __shared__ float sq[16 * 84];
    __shared__ float sk[16 * 84];
    __shared__ float sv[16 * 84];
    __shared__ float swt[16 * 17];

    const int g    = blockIdx.x;       // row in qkv = si*8 + b
    const int lane = threadIdx.x;      // 0..63
    const int b    = g & 7;
    const int si   = g >> 3;
    const int n    = si >> 6;
    const int w    = si & 63;

    const bf16* row = qkv + (size_t)g * QKV_N;

    for (int c = lane; c < 960; c += 64) {
        const int j = c * 4;
        ushort4 u = *(const ushort4*)(row + j);
        const int seg = j / 1280;
        const int within = j - seg * 1280;
        const int h = within / 80;
        const int d = within - h * 80;
        float* dst = (seg == 0 ? sq : (seg == 1 ? sk : sv)) + h * 84 + d;
        f32x4 v4 = {bf2f(u.x), bf2f(u.y), bf2f(u.z), bf2f(u.w)};
        *(f32x4*)dst = v4;
    }
    __syncthreads();

    const int g16  = lane & 15;
    const int quad = lane >> 4;
    const float scale = 0.11180339887498949f;  // 1/sqrt(80)
#pragma unroll
    for (int p = 0; p < 4; ++p) {
        const int h = quad * 4 + p;
        const f32x4* qv = (const f32x4*)(sq + h * 84);
        const f32x4* kv = (const f32x4*)(sk + g16 * 84);
        float s = 0.f;
#pragma unroll
        for (int d4 = 0; d4 < 20; ++d4) {
            const f32x4 a = qv[d4], bb = kv[d4];
            s += a[0] * bb[0] + a[1] * bb[1] + a[2] * bb[2] + a[3] * bb[3];
        }
        s *= scale;
        float mx = s;
#pragma unroll
        for (int m = 1; m < 16; m <<= 1)
            mx = fmaxf(mx, __shfl_xor(mx, m, 64));
        const float e = __expf(s - mx);
        float sum = e;
#pragma unroll
        for (int m = 1; m < 16; m <<= 1)
            sum += __shfl_xor(sum, m, 64);
        swt[h * 17 + g16] = e / sum;
    }
    __syncthreads();

    const int h2    = lane >> 2;
    const int dbase = (lane & 3) * 20;
    float accv[20];
#pragma unroll
    for (int t = 0; t < 20; ++t) accv[t] = 0.f;
    for (int gg = 0; gg < 16; ++gg) {
        const float wgt = swt[h2 * 17 + gg];
        const float* vp = sv + gg * 84 + dbase;
#pragma unroll
        for (int t = 0; t < 20; ++t) accv[t] += wgt * vp[t];
    }

    const size_t orow = (size_t)((n * 16 + h2) * 8 + b);
    bf16* op = aout + orow * ATT_K + w * 80 + dbase;
#pragma unroll
    for (int t = 0; t < 20; t += 2) {
        const unsigned int packed =
            ((unsigned int)f2bf(accv[t + 1]) << 16) | f2bf(accv[t]);
        *(unsigned int*)(op + t) = packed;
    }
}

extern "C" void kernel_launch(void* const* d_in, const int* in_sizes, int n_in,
                              void* d_out, int out_size, void* d_ws, size_t ws_size,
                              hipStream_t stream) {
    const void* x      = d_in[0];
    // d_in[1] = cu_seqlens (int64) — ignored by the module
    const void* qkv_w  = d_in[2];
    const void* qkv_b  = d_in[3];
    const void* proj_w = d_in[4];
    const void* proj_b = d_in[5];

    char* base   = (char*)d_ws;
    int*  flag   = (int*)base;
    bf16* xc     = (bf16*)(base + 256);
    bf16* qkvwc  = xc     + (size_t)M_QKV * D_MODEL;
    bf16* projwc = qkvwc  + (size_t)QKV_N * D_MODEL;
    bf16* qkvbc  = projwc + (size_t)D_MODEL * ATT_K;
    bf16* projbc = qkvbc  + QKV_N;
    bf16* qkv    = projbc + D_MODEL;
    bf16* aout   = xc;     // alias: xc dead after GEMM1

    // 0) Detect input dtype.
    detect_dtype<<<1, 64, 0, stream>>>((const unsigned short*)x, flag);

    // 1) Canonicalize all inputs to bf16 in one launch.
    canon_all<<<(TOT4 + 255) / 256, 256, 0, stream>>>(
        x, qkv_w, proj_w, qkv_b, proj_b, xc, qkvwc, projwc, qkvbc, projbc, flag);

    // 2) QKV GEMM: xc[32768,1280] @ qkvwc[3840,1280]^T + qkvbc -> bf16 qkv
    gemm_bt_bias_256<<<(M_QKV / 256) * (QKV_N / 256), 512, 0, stream>>>(
        xc, qkvwc, qkvbc, qkv, M_QKV, QKV_N, D_MODEL, nullptr);

    // 3) Windowed attention over heads: one wave per (si, b)
    win_attn<<<M_QKV, 64, 0, stream>>>(qkv, aout);

    // 4) Proj GEMM: aout[8192,5120] @ projwc[1280,5120]^T + projbc -> d_out
    gemm_bt_bias_256<<<(M_PROJ / 256) * (D_MODEL / 256), 512, 0, stream>>>(
        aout, projwc, projbc, d_out, M_PROJ, D_MODEL, ATT_K, flag);
}

// Round 8
// 891.588 us; speedup vs baseline: 1.0794x; 1.0794x over previous
//
#include <hip/hip_runtime.h>
#include <hip/hip_bf16.h>
#include <stdint.h>

typedef __hip_bfloat16 bf16;
typedef __attribute__((ext_vector_type(8))) short short8;
typedef __attribute__((ext_vector_type(4))) float f32x4;

// Problem constants
#define S_LEN   4096
#define BATCH   8
#define D_MODEL 1280
#define NHEADS  16
#define DHEAD   80
#define WIN     64
#define NWIN    (S_LEN / WIN)            // 64
#define QKV_N   (3 * D_MODEL)            // 3840
#define ATT_K   (WIN * DHEAD)            // 5120
#define M_QKV   (S_LEN * BATCH)          // 32768
#define M_PROJ  (NWIN * NHEADS * BATCH)  // 8192
#define OUT_ELEMS ((size_t)M_PROJ * D_MODEL) // 10,485,760

// canon segment sizes (in 4-element chunks)
#define NX4   (M_QKV * D_MODEL / 4)
#define NQW4  (QKV_N * D_MODEL / 4)
#define NPW4  (D_MODEL * ATT_K / 4)
#define NQB4  (QKV_N / 4)
#define NPB4  (D_MODEL / 4)
#define TOT4  (NX4 + NQW4 + NPW4 + NQB4 + NPB4)

__device__ __forceinline__ float bf2f(unsigned short b) {
    union { unsigned int i; float f; } v;
    v.i = ((unsigned int)b) << 16;
    return v.f;
}

__device__ __forceinline__ unsigned short f2bf(float f) {
    __hip_bfloat16 h = __float2bfloat16(f);
    return *reinterpret_cast<unsigned short*>(&h);
}

// ---------------------------------------------------------------------------
// Dtype detection (fp32 inputs -> flag=1, bf16 -> flag=0).
// ---------------------------------------------------------------------------
__global__ void detect_dtype(const unsigned short* __restrict__ x,
                             int* __restrict__ flag) {
    const int lane = threadIdx.x;  // 64
    int big = 0;
    for (int j = lane; j < 256; j += 64) {
        unsigned short u = x[2 * j];
        int e = (u >> 7) & 0xFF;
        big += (e >= 135) ? 1 : 0;
    }
#pragma unroll
    for (int m = 1; m < 64; m <<= 1) big += __shfl_xor(big, m, 64);
    if (lane == 0) *flag = (big >= 8) ? 1 : 0;
}

// ---------------------------------------------------------------------------
// One merged canonicalization kernel for all 5 float inputs -> bf16 copies.
// ---------------------------------------------------------------------------
__global__ __launch_bounds__(256) void canon_all(
    const void* __restrict__ x,  const void* __restrict__ qw,
    const void* __restrict__ pw, const void* __restrict__ qb,
    const void* __restrict__ pb,
    bf16* __restrict__ xc, bf16* __restrict__ qwc, bf16* __restrict__ pwc,
    bf16* __restrict__ qbc, bf16* __restrict__ pbc,
    const int* __restrict__ flag) {
    const int f = *flag;
    const long i = (long)blockIdx.x * 256 + threadIdx.x;
    if (i >= TOT4) return;
    const void* src; bf16* dst; long j;
    if (i < NX4)                        { src = x;  dst = xc;  j = i; }
    else if (i < NX4 + NQW4)            { src = qw; dst = qwc; j = i - NX4; }
    else if (i < NX4 + NQW4 + NPW4)     { src = pw; dst = pwc; j = i - NX4 - NQW4; }
    else if (i < NX4 + NQW4 + NPW4 + NQB4) { src = qb; dst = qbc; j = i - NX4 - NQW4 - NPW4; }
    else                                { src = pb; dst = pbc; j = i - NX4 - NQW4 - NPW4 - NQB4; }
    if (f) {
        const float4 v = ((const float4*)src)[j];
        ushort4 o;
        o.x = f2bf(v.x); o.y = f2bf(v.y); o.z = f2bf(v.z); o.w = f2bf(v.w);
        ((ushort4*)dst)[j] = o;
    } else {
        ((ushort4*)dst)[j] = ((const ushort4*)src)[j];
    }
}

__device__ __forceinline__ void gload16(const bf16* g, bf16* l) {
    __builtin_amdgcn_global_load_lds(
        (const __attribute__((address_space(1))) void*)g,
        (__attribute__((address_space(3))) void*)l, 16, 0, 0);
}

// ---------------------------------------------------------------------------
// 256x256 BT GEMM, single-barrier-per-K-tile overlapped schedule.
// C[M,N] = A[M,K] @ B[N,K]^T + bias[N]. bf16 in, fp32 accumulate.
//
// R6 post-mortem: the 8-phase (2-barrier/phase) port measured 37% MfmaUtil,
// 5958 cyc/K-tile == serial LDS-service (~2300) + MFMA (~2480) + 8 barriers.
// Lockstep barriers prevented LDS/MFMA overlap. This version exploits that
// within a K-tile ALL ds_reads hit buf `cur` and ALL stages hit `cur^1`
// (1-deep prefetch), so no intra-K-tile barrier is needed:
//
//   per K-tile: vmcnt(0) [latency-hidden: drains loads issued ~3500cyc ago]
//               s_barrier + sched_barrier(0)
//               LDA(0),LDB(0),LDB(1)  16x ds_read_b128   (buf cur)
//               STAGE x4 -> 8x global_load_lds           (buf cur^1, kt+1)
//               MFMA Q(0,0), Q(0,1)   [compiler emits lgkmcnt(4)/(0);
//                                      bfr1+stage service under Q(0,0)]
//               LDA(1)                8x ds_read (af reuse, WAR by compiler)
//               MFMA Q(1,1), Q(1,0)   [LDA(1) serviced under Q(0,1)]
//
// Hazards: each wave's reads complete before its barrier arrival (consumed
// by MFMAs); stage-writes into cur^1 are issued post-barrier => cannot race
// kt-1's reads of cur^1. vmcnt(0)+barrier publishes kt's buffer. Register
// budget unchanged (af reused for mh1); launch_bounds(512) pins <=256 regs.
//
// Geometry: BM=BN=256, BK=64, 512 thr = 8 waves (2M x 4N), per-wave 128x64
// out = acc[8][4] f32x4. LDS [2][256][64] bf16 x2 = 128 KiB, 1 block/CU.
// Swizzle: 16B chunks, physical = logical ^ (row&7), pre-swizzled global
// source + linear gload_lds dest + XOR on read (involution both sides).
// ---------------------------------------------------------------------------
__global__ __launch_bounds__(512) void gemm_bt_bias_256(
    const bf16* __restrict__ A, const bf16* __restrict__ B,
    const bf16* __restrict__ bias, void* __restrict__ Cout,
    int M, int N, int K, const int* __restrict__ out_f32)
{
    __shared__ bf16 sA[2][256 * 64];
    __shared__ bf16 sB[2][256 * 64];

    const int t    = threadIdx.x;        // 0..511
    const int lane = t & 63;
    const int wave = t >> 6;             // 0..7
    const int wm   = wave >> 2;          // 0..1
    const int wn   = wave & 3;           // 0..3
    const int quad = lane >> 4;
    const int l16  = lane & 15;
    const int l7   = l16 & 7;

    // Block swizzle: XCD slab (bijective; both grids are multiples of 8)
    // + GROUP_M chunks inside the slab for L2 reuse.
    const int B_nb = N >> 8, B_mb = M >> 8;
    const int mpx  = B_mb >> 3;                 // m-blocks per XCD
    const int gm   = (mpx >= 8) ? 8 : mpx;      // 8 for QKV, 4 for proj
    const int gid  = blockIdx.x;
    const int xcd  = gid & 7;
    const int per  = gid >> 3;
    const int grp  = per / (gm * B_nb);
    const int rem  = per - grp * (gm * B_nb);
    const int bn   = rem / gm;
    const int bm   = xcd * mpx + grp * gm + (rem - bn * gm);

    // Staging: thread t covers row t>>3 (of 64/issue), physical chunk t&7,
    // global chunk (t&7)^(row&7). Row offsets below are multiples of 8, so
    // tchunk is issue-invariant.
    const int trow   = t >> 3;
    const int tchunk = (t & 7) ^ (trow & 7);
    const bf16* Ag = A + (size_t)(bm * 256 + trow) * K + tchunk * 8;
    const bf16* Bg = B + (size_t)(bn * 256 + trow) * K + tchunk * 8;
    const int nt = K >> 6;

#define STAGE(hx, kt_)                                                       \
  do {                                                                       \
    const int _b = (kt_) & 1;                                                \
    if ((hx) == 0 || (hx) == 2) {                                            \
      const int _h = ((hx) == 2) ? 128 : 0;                                  \
      gload16(Ag + (size_t)(_h) * K + (size_t)(kt_) * 64,                    \
              &sA[_b][_h * 64 + wave * 512]);                                \
      gload16(Ag + (size_t)(_h + 64) * K + (size_t)(kt_) * 64,               \
              &sA[_b][(_h + 64) * 64 + wave * 512]);                         \
    } else {                                                                 \
      const int _h = ((hx) == 3) ? 128 : 0;                                  \
      gload16(Bg + (size_t)(_h) * K + (size_t)(kt_) * 64,                    \
              &sB[_b][_h * 64 + wave * 512]);                                \
      gload16(Bg + (size_t)(_h + 64) * K + (size_t)(kt_) * 64,               \
              &sB[_b][(_h + 64) * 64 + wave * 512]);                         \
    }                                                                        \
  } while (0)

    f32x4 acc[8][4];
#pragma unroll
    for (int i = 0; i < 8; ++i)
#pragma unroll
        for (int j = 0; j < 4; ++j)
            acc[i][j] = (f32x4){0.f, 0.f, 0.f, 0.f};

    short8 af[4][2];        // A frags of the active mh (i, kchunk) — reused
    short8 bfr[2][2][2];    // B frags of BOTH nh halves ([nh][jj][kchunk])
    const int pc0 = quad ^ l7;          // swizzled chunk, kchunk 0
    const int pc1 = (quad + 4) ^ l7;    // swizzled chunk, kchunk 1

#define LDA(mh)                                                              \
  do {                                                                       \
    const bf16* _ab = &sA[cur][((mh) * 128 + wm * 64 + l16) * 64];           \
    _Pragma("unroll")                                                        \
    for (int _i = 0; _i < 4; ++_i) {                                         \
      af[_i][0] = *(const short8*)(_ab + _i * 1024 + pc0 * 8);               \
      af[_i][1] = *(const short8*)(_ab + _i * 1024 + pc1 * 8);               \
    }                                                                        \
  } while (0)

#define LDB(nh)                                                              \
  do {                                                                       \
    const bf16* _bb = &sB[cur][((nh) * 128 + wn * 32 + l16) * 64];           \
    _Pragma("unroll")                                                        \
    for (int _j = 0; _j < 2; ++_j) {                                         \
      bfr[nh][_j][0] = *(const short8*)(_bb + _j * 1024 + pc0 * 8);          \
      bfr[nh][_j][1] = *(const short8*)(_bb + _j * 1024 + pc1 * 8);          \
    }                                                                        \
  } while (0)

#define MFMA_Q(mh, nh)                                                       \
  do {                                                                       \
    _Pragma("unroll")                                                        \
    for (int _i = 0; _i < 4; ++_i)                                           \
      _Pragma("unroll")                                                      \
      for (int _j = 0; _j < 2; ++_j) {                                       \
        acc[(mh) * 4 + _i][(nh) * 2 + _j] =                                  \
            __builtin_amdgcn_mfma_f32_16x16x32_bf16(                         \
                af[_i][0], bfr[nh][_j][0],                                   \
                acc[(mh) * 4 + _i][(nh) * 2 + _j], 0, 0, 0);                 \
        acc[(mh) * 4 + _i][(nh) * 2 + _j] =                                  \
            __builtin_amdgcn_mfma_f32_16x16x32_bf16(                         \
                af[_i][1], bfr[nh][_j][1],                                   \
                acc[(mh) * 4 + _i][(nh) * 2 + _j], 0, 0, 0);                 \
      }                                                                      \
  } while (0)

    // Prologue: stage kt0 fully (8 loads). The kt=0 gate pays full latency
    // once; steady-state gates drain loads issued one K-tile (~3500 cyc) ago.
    STAGE(0, 0); STAGE(1, 0); STAGE(2, 0); STAGE(3, 0);

    int cur = 0;
    for (int kt = 0; kt < nt; ++kt) {
        // Publish buffer `cur` (each wave certifies its own stage loads,
        // barrier makes it block-wide). No other barrier in the K-tile.
        asm volatile("s_waitcnt vmcnt(0)" ::: "memory");
        __builtin_amdgcn_s_barrier();
        __builtin_amdgcn_sched_barrier(0);   // pin reads/stages below barrier

        // Front reads: af(mh0) + both B halves. 16 ds_read_b128.
        LDA(0); LDB(0); LDB(1);
        // Prefetch kt+1 into cur^1 (8 global_load_lds, vmcnt only).
        if (kt + 1 < nt) {
            STAGE(0, kt + 1); STAGE(1, kt + 1);
            STAGE(2, kt + 1); STAGE(3, kt + 1);
        }

        // Compiler emits counted lgkm waits: Q(0,0) waits af+bfr0 only;
        // bfr1 + stage service hide under it.
        __builtin_amdgcn_s_setprio(1);
        MFMA_Q(0, 0);
        MFMA_Q(0, 1);
        __builtin_amdgcn_s_setprio(0);

        // Reload af with mh1 (WAR on af resolved by compiler ordering);
        // service hides under Q(0,1)'s tail.
        LDA(1);

        __builtin_amdgcn_s_setprio(1);
        MFMA_Q(1, 1);
        MFMA_Q(1, 0);
        __builtin_amdgcn_s_setprio(0);

        cur ^= 1;
    }
#undef STAGE
#undef LDA
#undef LDB
#undef MFMA_Q

    // Epilogue: C/D layout col = lane&15, row = quad*4 + reg.
    const int outf = out_f32 ? *out_f32 : 0;
    const int crow0 = bm * 256 + wm * 64 + quad * 4;
    const int ccol0 = bn * 256 + wn * 32 + l16;
    if (outf) {
        float* Cf = (float*)Cout;
#pragma unroll
        for (int mh = 0; mh < 2; ++mh)
#pragma unroll
        for (int nh = 0; nh < 2; ++nh)
#pragma unroll
        for (int j = 0; j < 2; ++j) {
            const int col = ccol0 + nh * 128 + j * 16;
            const float bv = bf2f(*(const unsigned short*)&bias[col]);
#pragma unroll
            for (int i = 0; i < 4; ++i) {
                const int row = crow0 + mh * 128 + i * 16;
#pragma unroll
                for (int r = 0; r < 4; ++r)
                    Cf[(size_t)(row + r) * N + col] =
                        acc[mh * 4 + i][nh * 2 + j][r] + bv;
            }
        }
    } else {
        bf16* Cb = (bf16*)Cout;
#pragma unroll
        for (int mh = 0; mh < 2; ++mh)
#pragma unroll
        for (int nh = 0; nh < 2; ++nh)
#pragma unroll
        for (int j = 0; j < 2; ++j) {
            const int col = ccol0 + nh * 128 + j * 16;
            const float bv = bf2f(*(const unsigned short*)&bias[col]);
#pragma unroll
            for (int i = 0; i < 4; ++i) {
                const int row = crow0 + mh * 128 + i * 16;
#pragma unroll
                for (int r = 0; r < 4; ++r)
                    Cb[(size_t)(row + r) * N + col] =
                        __float2bfloat16(acc[mh * 4 + i][nh * 2 + j][r] + bv);
            }
        }
    }
}

// ---------------------------------------------------------------------------
// Windowed attention over the head axis. One wave per (si, b) pair.
// ---------------------------------------------------------------------------
__global__ __launch_bounds__(64) void win_attn(
    const bf16* __restrict__ qkv,   // [32768, 3840]
    bf16* __restrict__ aout)        // [8192, 5120]
{
    __shared__ float sq[16 * 84];
    __shared__ float sk[16 * 84];
    __shared__ float sv[16 * 84];
    __shared__ float swt[16 * 17];

    const int g    = blockIdx.x;       // row in qkv = si*8 + b
    const int lane = threadIdx.x;      // 0..63
    const int b    = g & 7;
    const int si   = g >> 3;
    const int n    = si >> 6;
    const int w    = si & 63;

    const bf16* row = qkv + (size_t)g * QKV_N;

    for (int c = lane; c < 960; c += 64) {
        const int j = c * 4;
        ushort4 u = *(const ushort4*)(row + j);
        const int seg = j / 1280;
        const int within = j - seg * 1280;
        const int h = within / 80;
        const int d = within - h * 80;
        float* dst = (seg == 0 ? sq : (seg == 1 ? sk : sv)) + h * 84 + d;
        f32x4 v4 = {bf2f(u.x), bf2f(u.y), bf2f(u.z), bf2f(u.w)};
        *(f32x4*)dst = v4;
    }
    __syncthreads();

    const int g16  = lane & 15;
    const int quad = lane >> 4;
    const float scale = 0.11180339887498949f;  // 1/sqrt(80)
#pragma unroll
    for (int p = 0; p < 4; ++p) {
        const int h = quad * 4 + p;
        const f32x4* qv = (const f32x4*)(sq + h * 84);
        const f32x4* kv = (const f32x4*)(sk + g16 * 84);
        float s = 0.f;
#pragma unroll
        for (int d4 = 0; d4 < 20; ++d4) {
            const f32x4 a = qv[d4], bb = kv[d4];
            s += a[0] * bb[0] + a[1] * bb[1] + a[2] * bb[2] + a[3] * bb[3];
        }
        s *= scale;
        float mx = s;
#pragma unroll
        for (int m = 1; m < 16; m <<= 1)
            mx = fmaxf(mx, __shfl_xor(mx, m, 64));
        const float e = __expf(s - mx);
        float sum = e;
#pragma unroll
        for (int m = 1; m < 16; m <<= 1)
            sum += __shfl_xor(sum, m, 64);
        swt[h * 17 + g16] = e / sum;
    }
    __syncthreads();

    const int h2    = lane >> 2;
    const int dbase = (lane & 3) * 20;
    float accv[20];
#pragma unroll
    for (int t = 0; t < 20; ++t) accv[t] = 0.f;
    for (int gg = 0; gg < 16; ++gg) {
        const float wgt = swt[h2 * 17 + gg];
        const float* vp = sv + gg * 84 + dbase;
#pragma unroll
        for (int t = 0; t < 20; ++t) accv[t] += wgt * vp[t];
    }

    const size_t orow = (size_t)((n * 16 + h2) * 8 + b);
    bf16* op = aout + orow * ATT_K + w * 80 + dbase;
#pragma unroll
    for (int t = 0; t < 20; t += 2) {
        const unsigned int packed =
            ((unsigned int)f2bf(accv[t + 1]) << 16) | f2bf(accv[t]);
        *(unsigned int*)(op + t) = packed;
    }
}

extern "C" void kernel_launch(void* const* d_in, const int* in_sizes, int n_in,
                              void* d_out, int out_size, void* d_ws, size_t ws_size,
                              hipStream_t stream) {
    const void* x      = d_in[0];
    // d_in[1] = cu_seqlens (int64) — ignored by the module
    const void* qkv_w  = d_in[2];
    const void* qkv_b  = d_in[3];
    const void* proj_w = d_in[4];
    const void* proj_b = d_in[5];

    char* base   = (char*)d_ws;
    int*  flag   = (int*)base;
    bf16* xc     = (bf16*)(base + 256);
    bf16* qkvwc  = xc     + (size_t)M_QKV * D_MODEL;
    bf16* projwc = qkvwc  + (size_t)QKV_N * D_MODEL;
    bf16* qkvbc  = projwc + (size_t)D_MODEL * ATT_K;
    bf16* projbc = qkvbc  + QKV_N;
    bf16* qkv    = projbc + D_MODEL;
    bf16* aout   = xc;     // alias: xc dead after GEMM1

    // 0) Detect input dtype.
    detect_dtype<<<1, 64, 0, stream>>>((const unsigned short*)x, flag);

    // 1) Canonicalize all inputs to bf16 in one launch.
    canon_all<<<(TOT4 + 255) / 256, 256, 0, stream>>>(
        x, qkv_w, proj_w, qkv_b, proj_b, xc, qkvwc, projwc, qkvbc, projbc, flag);

    // 2) QKV GEMM: xc[32768,1280] @ qkvwc[3840,1280]^T + qkvbc -> bf16 qkv
    gemm_bt_bias_256<<<(M_QKV / 256) * (QKV_N / 256), 512, 0, stream>>>(
        xc, qkvwc, qkvbc, qkv, M_QKV, QKV_N, D_MODEL, nullptr);

    // 3) Windowed attention over heads: one wave per (si, b)
    win_attn<<<M_QKV, 64, 0, stream>>>(qkv, aout);

    // 4) Proj GEMM: aout[8192,5120] @ projwc[1280,5120]^T + projbc -> d_out
    gemm_bt_bias_256<<<(M_PROJ / 256) * (D_MODEL / 256), 512, 0, stream>>>(
        aout, projwc, projbc, d_out, M_PROJ, D_MODEL, ATT_K, flag);
}